// Round 5
// baseline (295.359 us; speedup 1.0000x reference)
//
#include <hip/hip_runtime.h>
#include <stdint.h>

#define NBATCH 16
#define HW_ (1 << 20)            // 1024*1024 per batch
#define TPB 256

#define NBPB_H 32                // blocks per batch for hist pass
#define TPB_H 1024               // 16 waves/block, 2 blocks/CU -> 100% occupancy
#define EPB_H (HW_ / NBPB_H)     // 32768 elements per block
#define ITER_H (EPB_H / (TPB_H * 4)) // 8 float4 per thread

#define NBINS 8192               // fine bins on score_bits >> 12; base 0x3F400
#define FBASE 0x3F400

#define TPB_RF 1024              // redfind threads (8 bins per thread)

#define NBPB_F 256               // blocks per batch for main pass
#define FCHUNK (HW_ / NBPB_F)    // 4096 elements per block

#define CAND_CAP 32768           // ambiguous candidates per batch
#define LCAP 512                 // per-block LDS candidate capacity
#define TIE_CAP 4096
#define CNT_STRIDE 64            // u32 stride between per-batch counters (256 B)

typedef float f4v __attribute__((ext_vector_type(4)));

struct BParams {
    unsigned int k;        // n_train
    unsigned int bin1f;    // selected fine bin as raw (score_bits>>12) value; 0xFFFFFFFF if k==0
    unsigned int r;        // rank remaining within bin1f (k - count_above)
    unsigned int mode;     // 0 = no train, 1 = normal
};

__device__ __forceinline__ unsigned int score_bits(float p, int m) {
    bool correct = (p > 0.5f) == (m == 1);
    float conf = fmaxf(p, 1.0f - p);
    float base = correct ? ((conf > 0.85f) ? 1.0f : 2.0f)
                         : ((conf > 0.85f) ? 4.0f : 3.0f);
    float bonus = (conf - 0.5f) * 0.5f;   // exact in f32
    float s = correct ? (base - bonus) : (base + bonus);
    return __float_as_uint(s);            // positive floats: bit order == value order
}

__device__ __forceinline__ float agent_load_f32(const float* p) {
    return __hip_atomic_load(p, __ATOMIC_RELAXED, __HIP_MEMORY_SCOPE_AGENT);
}

// Pass 1: per-block private 8192-bin histogram in LDS, flushed as u16-packed
// words (count <= 32768 fits u16) to a distinct global slice. No global atomics.
__global__ void k_hist1(const float4* __restrict__ pred4, const int4* __restrict__ mask4,
                        unsigned int* __restrict__ hist_part16) {
    __shared__ unsigned int lh[NBINS];
    int b = blockIdx.x / NBPB_H;
    int blk = blockIdx.x % NBPB_H;
    int t = threadIdx.x;
    for (int i = t; i < NBINS; i += TPB_H) lh[i] = 0;
    __syncthreads();
    size_t gb = (size_t)b * (HW_ / 4) + (size_t)blk * (EPB_H / 4);
    // software prefetch-1 pipeline
    float4 p = pred4[gb + t];
    int4 m = mask4[gb + t];
#pragma unroll
    for (int j = 0; j < ITER_H; j++) {
        float4 pc = p;
        int4 mc = m;
        if (j + 1 < ITER_H) {
            p = pred4[gb + (size_t)(j + 1) * TPB_H + t];
            m = mask4[gb + (size_t)(j + 1) * TPB_H + t];
        }
        float pa[4] = {pc.x, pc.y, pc.z, pc.w};
        int ma[4] = {mc.x, mc.y, mc.z, mc.w};
#pragma unroll
        for (int l = 0; l < 4; l++) {
            if (ma[l] != 2) {
                unsigned int sb = score_bits(pa[l], ma[l]);
                int fb = (int)(sb >> 12) - FBASE;
                fb = min(max(fb, 0), NBINS - 1);
                atomicAdd(&lh[fb], 1u);
            }
        }
    }
    __syncthreads();
    // flush: pack 2 bins per u32 (u16 counts), coalesced stores
    unsigned int* hp = hist_part16 + (size_t)(b * NBPB_H + blk) * (NBINS / 2);
    for (int w = t; w < NBINS / 2; w += TPB_H)
        hp[w] = (lh[2 * w] & 0xFFFFu) | (lh[2 * w + 1] << 16);
}

// Fused reduce+find: 16 blocks x 1024 threads. Thread t sums bins [8t,8t+8)
// across the 32 u16-packed partials (coalesced uint4 loads, deep MLP), then a
// 1024-wide suffix scan selects the fine bin containing the k-th largest.
__global__ void k_redfind(const unsigned int* __restrict__ hist_part16,
                          BParams* __restrict__ prm) {
    int b = blockIdx.x;
    int t = threadIdx.x;
    __shared__ unsigned int cs_[TPB_RF + 1];
    unsigned int c[8];
#pragma unroll
    for (int j = 0; j < 8; j++) c[j] = 0;
#pragma unroll
    for (int p = 0; p < NBPB_H; p++) {
        const uint4* hp = (const uint4*)(hist_part16 + (size_t)(b * NBPB_H + p) * (NBINS / 2));
        uint4 w = hp[t];
        c[0] += w.x & 0xFFFFu; c[1] += w.x >> 16;
        c[2] += w.y & 0xFFFFu; c[3] += w.y >> 16;
        c[4] += w.z & 0xFFFFu; c[5] += w.z >> 16;
        c[6] += w.w & 0xFFFFu; c[7] += w.w >> 16;
    }
    unsigned int s = 0;
#pragma unroll
    for (int j = 0; j < 8; j++) s += c[j];
    cs_[t] = s;
    if (t == 0) cs_[TPB_RF] = 0;
    __syncthreads();
    for (int off = 1; off < TPB_RF; off <<= 1) {
        unsigned int a = (t + off < TPB_RF) ? cs_[t + off] : 0u;
        __syncthreads();
        cs_[t] += a;
        __syncthreads();
    }
    unsigned int n = cs_[0];                       // total annotated
    unsigned int k = (unsigned int)(int)((float)n * 0.5f);  // astype(f32)*0.5 -> int32
    if (k == 0) {
        if (t == 0) {
            BParams P;
            P.k = 0; P.bin1f = 0xFFFFFFFFu; P.r = 0; P.mode = 0;
            prm[b] = P;
        }
        return;
    }
    if (cs_[t] >= k && cs_[t + 1] < k) {           // unique boundary thread
        unsigned int cum = cs_[t + 1];
#pragma unroll
        for (int j = 7; j >= 0; j--) {
            unsigned int hb = c[j];
            if (cum + hb >= k) {
                BParams P;
                P.k = k;
                P.bin1f = (unsigned int)(FBASE + t * 8 + j);
                P.r = k - cum;
                P.mode = 1;
                prm[b] = P;
                break;
            }
            cum += hb;
        }
    }
}

// Main fused pass: prefetch-1 input pipeline, in-loop shfl-aligned float4 stores
// (stores overlap compute; LDS lcode kept only for wave-boundary/head/tail fixups),
// BCE for definite-train, LDS candidate staging, one global atomic per block.
__global__ void k_main(const float4* __restrict__ pred4, const int4* __restrict__ mask4,
                       const BParams* __restrict__ prm, float* __restrict__ out,
                       float* __restrict__ partials, unsigned int* __restrict__ cand_cnt,
                       unsigned int* __restrict__ cand_idx, unsigned int* __restrict__ cand_sb,
                       float* __restrict__ cand_bce) {
    int b = blockIdx.x / NBPB_F;
    int blk = blockIdx.x % NBPB_F;
    BParams P = prm[b];
    unsigned int target = P.bin1f;
    __shared__ unsigned int lcode[FCHUNK / 4];   // code word per input quad
    __shared__ float red[TPB];
    __shared__ unsigned int l_idx[LCAP];
    __shared__ unsigned int l_sb[LCAP];
    __shared__ float l_bce[LCAP];
    __shared__ unsigned int lcnt;
    __shared__ unsigned int gbase;
    if (threadIdx.x == 0) lcnt = 0;
    __syncthreads();
    float acc = 0.0f;
    int ibase = blk * FCHUNK;
    size_t base4 = (size_t)b * (HW_ / 4) + (size_t)(ibase / 4);
    float* trout = out + 1;
    float* hoout = out + 1 + (size_t)NBATCH * HW_;
    size_t Gbase = (size_t)b * HW_ + (size_t)ibase;
    int lane = threadIdx.x & 63;
    // prefetch-1 pipeline over the 4 staging iterations
    float4 p = pred4[base4 + threadIdx.x];
    int4 m = mask4[base4 + threadIdx.x];
#pragma unroll
    for (int j = 0; j < FCHUNK / (TPB * 4); j++) {   // 4 iterations
        int v = j * TPB + threadIdx.x;               // word index [0,1024)
        float4 pc = p;
        int4 mc = m;
        if (j + 1 < FCHUNK / (TPB * 4)) {
            p = pred4[base4 + (size_t)(j + 1) * TPB + threadIdx.x];
            m = mask4[base4 + (size_t)(j + 1) * TPB + threadIdx.x];
        }
        float pa[4] = {pc.x, pc.y, pc.z, pc.w};
        int ma[4] = {mc.x, mc.y, mc.z, mc.w};
        unsigned int cw = 0;
#pragma unroll
        for (int l = 0; l < 4; l++) {
            bool ann = (ma[l] != 2);
            unsigned int sb = score_bits(pa[l], ma[l]);
            unsigned int fine = sb >> 12;
            bool tr = ann && (fine > target);
            bool amb = ann && (fine == target);
            unsigned int code = (tr ? 1u : 0u) | ((ann && !tr) ? 2u : 0u);
            cw |= code << (8 * l);
            float bce = 0.0f;
            if (tr || amb) {
                float pc2 = fminf(fmaxf(pa[l], 1e-7f), 1.0f - 1e-7f);
                bce = (ma[l] == 1) ? -__logf(pc2) : -__logf(1.0f - pc2);
            }
            if (tr) acc += bce;
            if (amb) {
                unsigned int p0 = atomicAdd(&lcnt, 1u);  // LDS atomic
                if (p0 < LCAP) {
                    l_idx[p0] = (unsigned int)(ibase + v * 4 + l);
                    l_sb[p0] = sb;
                    l_bce[p0] = bce;
                } else {
                    unsigned int gp = atomicAdd(&cand_cnt[b * CNT_STRIDE], 1u);
                    if (gp < CAND_CAP) {
                        size_t o = (size_t)b * CAND_CAP + gp;
                        cand_idx[o] = (unsigned int)(ibase + v * 4 + l);
                        cand_sb[o] = sb;
                        cand_bce[o] = bce;
                    }
                }
            }
        }
        lcode[v] = cw;   // stride-1 ds_write_b32 (boundary/head/tail fixups)
        // in-loop aligned store: out-f4 at elem 3+4v needs byte3(cw) + bytes0..2
        // of the NEXT word, fetched from lane+1 via shuffle.
        unsigned int nw = (unsigned int)__shfl_down((int)cw, 1);
        if (lane != 63) {
            unsigned int c0 = cw >> 24;
            unsigned int c1 = nw & 0xFFu;
            unsigned int c2 = (nw >> 8) & 0xFFu;
            unsigned int c3 = (nw >> 16) & 0xFFu;
            int e = 3 + 4 * v;
            f4v tv = { (float)(c0 & 1u), (float)(c1 & 1u), (float)(c2 & 1u), (float)(c3 & 1u) };
            f4v hv = { (float)((c0 >> 1) & 1u), (float)((c1 >> 1) & 1u),
                       (float)((c2 >> 1) & 1u), (float)((c3 >> 1) & 1u) };
            *(f4v*)(trout + Gbase + e) = tv;
            *(f4v*)(hoout + Gbase + e) = hv;
        }
    }
    __syncthreads();
    // one global reservation per block, coalesced copy of LDS candidate list
    unsigned int n = min(lcnt, (unsigned int)LCAP);
    if (threadIdx.x == 0 && n > 0)
        gbase = atomicAdd(&cand_cnt[b * CNT_STRIDE], n);
    __syncthreads();
    for (unsigned int i = threadIdx.x; i < n; i += TPB) {
        unsigned int pos = gbase + i;
        if (pos < CAND_CAP) {
            size_t o = (size_t)b * CAND_CAP + pos;
            cand_idx[o] = l_idx[i];
            cand_sb[o] = l_sb[i];
            cand_bce[o] = l_bce[i];
        }
    }
    // wave-boundary fixups: words v = j*TPB + w*64 + 63 (skipped in-loop), except 1023
    if (threadIdx.x < 16) {
        int j = threadIdx.x >> 2, w = threadIdx.x & 3;
        int v = j * TPB + w * 64 + 63;
        if (v < FCHUNK / 4 - 1) {
            unsigned int w0 = lcode[v];
            unsigned int w1 = lcode[v + 1];
            unsigned int c0 = w0 >> 24;
            unsigned int c1 = w1 & 0xFFu;
            unsigned int c2 = (w1 >> 8) & 0xFFu;
            unsigned int c3 = (w1 >> 16) & 0xFFu;
            int e = 3 + 4 * v;
            f4v tv = { (float)(c0 & 1u), (float)(c1 & 1u), (float)(c2 & 1u), (float)(c3 & 1u) };
            f4v hv = { (float)((c0 >> 1) & 1u), (float)((c1 >> 1) & 1u),
                       (float)((c2 >> 1) & 1u), (float)((c3 >> 1) & 1u) };
            *(f4v*)(trout + Gbase + e) = tv;
            *(f4v*)(hoout + Gbase + e) = hv;
        }
    }
    if (threadIdx.x >= 16 && threadIdx.x < 19) {   // head elems 0,1,2
        int i = threadIdx.x - 16;
        unsigned int c = (lcode[0] >> (8 * i)) & 0xFFu;
        trout[Gbase + i] = (float)(c & 1u);
        hoout[Gbase + i] = (float)((c >> 1) & 1u);
    }
    if (threadIdx.x == 19) {  // tail elem 4095
        unsigned int c = (lcode[FCHUNK / 4 - 1] >> 24) & 0xFFu;
        trout[Gbase + FCHUNK - 1] = (float)(c & 1u);
        hoout[Gbase + FCHUNK - 1] = (float)((c >> 1) & 1u);
    }
    red[threadIdx.x] = acc;
    __syncthreads();
    for (int off = TPB / 2; off > 0; off >>= 1) {
        if (threadIdx.x < off) red[threadIdx.x] += red[threadIdx.x + off];
        __syncthreads();
    }
    if (threadIdx.x == 0) partials[blockIdx.x] = red[0];
}

// Fixup (fused with loss): exact low-12-bit select within candidates, tie-break on
// index, scatter-correct masks, accumulate tie BCE. One block per batch; the LAST
// block to finish (done-counter, 16 fences total) computes the final loss scalar.
__global__ void k_fixup(const unsigned int* __restrict__ cand_cnt,
                        const unsigned int* __restrict__ cand_idx,
                        const unsigned int* __restrict__ cand_sb,
                        const float* __restrict__ cand_bce,
                        const BParams* __restrict__ prm, float* __restrict__ out,
                        float* __restrict__ tie_partials,
                        const float* __restrict__ partials,
                        unsigned int* __restrict__ done_f) {
    int b = blockIdx.x;
    int t = threadIdx.x;
    __shared__ unsigned int h[4096];
    __shared__ unsigned int cs_[257];
    __shared__ unsigned int tie_idx[TIE_CAP];
    __shared__ unsigned int misc[8];  // [0]=v* [1]=T [2]=allTies [3]=tieCnt [4]=idxcut
    __shared__ float red[TPB];
    __shared__ double redd[TPB];
    __shared__ unsigned int lastf;
    BParams P = prm[b];
    float tieval = 0.0f;
    if (P.mode != 0) {
        unsigned int C = cand_cnt[b * CNT_STRIDE];
        if (C > CAND_CAP) C = CAND_CAP;
        const unsigned int* ci = cand_idx + (size_t)b * CAND_CAP;
        const unsigned int* cs = cand_sb + (size_t)b * CAND_CAP;
        const float* cb = cand_bce + (size_t)b * CAND_CAP;
        for (int i = t; i < 4096; i += TPB) h[i] = 0;
        if (t < 8) misc[t] = (t == 4) ? 0xFFFFFFFFu : 0u;
        __syncthreads();
        for (unsigned int i = t; i < C; i += TPB)
            atomicAdd(&h[cs[i] & 0xFFFu], 1u);
        __syncthreads();
        {
            unsigned int gs = 0;
#pragma unroll
            for (int j = 0; j < 16; j++) gs += h[t * 16 + j];
            cs_[t] = gs;
            if (t == 0) cs_[256] = 0;
        }
        __syncthreads();
        for (int off = 1; off < 256; off <<= 1) {
            unsigned int a = (t + off < 256) ? cs_[t + off] : 0u;
            __syncthreads();
            cs_[t] += a;
            __syncthreads();
        }
        if (cs_[t] >= P.r && cs_[t + 1] < P.r) {
            unsigned int cum = cs_[t + 1];
            for (int j = 15; j >= 0; j--) {
                unsigned int hb = h[t * 16 + j];
                if (cum + hb >= P.r) {
                    unsigned int T = P.r - cum;
                    misc[0] = (unsigned int)(t * 16 + j);
                    misc[1] = T;
                    misc[2] = (T == hb) ? 1u : 0u;
                    break;
                }
                cum += hb;
            }
        }
        __syncthreads();
        unsigned int vstar = misc[0], T = misc[1];
        bool allTies = (misc[2] != 0);
        unsigned int idxcut;
        if (allTies) {
            idxcut = 0xFFFFFFFFu;
        } else {
            for (unsigned int i = t; i < C; i += TPB) {
                if ((cs[i] & 0xFFFu) == vstar) {
                    unsigned int p = atomicAdd(&misc[3], 1u);
                    if (p < TIE_CAP) tie_idx[p] = ci[i];
                }
            }
            __syncthreads();
            unsigned int E2 = misc[3];
            if (E2 > TIE_CAP) E2 = TIE_CAP;
            for (unsigned int i = t; i < E2; i += TPB) {
                unsigned int vi = tie_idx[i];
                unsigned int cnt = 0;
                for (unsigned int j = 0; j < E2; j++) cnt += (tie_idx[j] < vi) ? 1u : 0u;
                if (cnt == T - 1) misc[4] = vi;  // T-th smallest tie index
            }
            __syncthreads();
            idxcut = misc[4];
        }
        float acc = 0.0f;
        float* trout = out + 1;
        float* hoout = out + 1 + (size_t)NBATCH * HW_;
        size_t base = (size_t)b * HW_;
        for (unsigned int i = t; i < C; i += TPB) {
            unsigned int low = cs[i] & 0xFFFu;
            bool tr = (low > vstar) || (low == vstar && ci[i] <= idxcut);
            if (tr) {
                trout[base + ci[i]] = 1.0f;
                hoout[base + ci[i]] = 0.0f;
                acc += cb[i];
            }
        }
        red[t] = acc;
        __syncthreads();
        for (int off = TPB / 2; off > 0; off >>= 1) {
            if (t < off) red[t] += red[t + off];
            __syncthreads();
        }
        if (t == 0) tieval = red[0];
    }
    // ---- publish tie partial + last-block loss ----
    if (t == 0)
        __hip_atomic_store(&tie_partials[b], tieval, __ATOMIC_RELAXED, __HIP_MEMORY_SCOPE_AGENT);
    __threadfence();
    __syncthreads();
    if (t == 0) lastf = (atomicAdd(done_f, 1u) == (unsigned int)(NBATCH - 1)) ? 1u : 0u;
    __syncthreads();
    if (!lastf) return;
    __threadfence();
    double s = 0.0;
    for (int i = t; i < NBATCH * NBPB_F; i += TPB) s += (double)partials[i];
    if (t < NBATCH) s += (double)agent_load_f32(&tie_partials[t]);
    redd[t] = s;
    __syncthreads();
    for (int off = TPB / 2; off > 0; off >>= 1) {
        if (t < off) redd[t] += redd[t + off];
        __syncthreads();
    }
    if (t == 0) {
        unsigned long long den = 0;
        for (int b2 = 0; b2 < NBATCH; b2++) den += prm[b2].k;
        float denf = (float)den + 1e-7f;
        out[0] = (float)redd[0] / denf;
    }
}

extern "C" void kernel_launch(void* const* d_in, const int* in_sizes, int n_in,
                              void* d_out, int out_size, void* d_ws, size_t ws_size,
                              hipStream_t stream) {
    const float4* pred4 = (const float4*)d_in[0];
    const int4* mask4 = (const int4*)d_in[1];
    float* out = (float*)d_out;

    // workspace layout (u32 words): zeroed region (cand_cnt + done) first.
    unsigned int* cand_cnt = (unsigned int*)d_ws;                     // 16*CNT_STRIDE = 1024
    unsigned int* done_f = cand_cnt + NBATCH * CNT_STRIDE;            // 32 (only [0] used)
    BParams* prm = (BParams*)(done_f + 32);                           // 16 structs
    float* partials = (float*)(prm + NBATCH);                         // 16*256
    float* tie_partials = partials + NBATCH * NBPB_F;                 // 16
    unsigned int* cand_idx = (unsigned int*)(tie_partials + NBATCH);  // 16*32768
    unsigned int* cand_sb = cand_idx + NBATCH * CAND_CAP;
    float* cand_bce = (float*)(cand_sb + NBATCH * CAND_CAP);
    unsigned int* hist_part16 = (unsigned int*)(cand_bce + NBATCH * CAND_CAP); // 16*32*4096

    size_t zero_bytes = (size_t)(NBATCH * CNT_STRIDE + 32) * 4;
    hipMemsetAsync(d_ws, 0, zero_bytes, stream);

    k_hist1<<<dim3(NBATCH * NBPB_H), dim3(TPB_H), 0, stream>>>(pred4, mask4, hist_part16);
    k_redfind<<<dim3(NBATCH), dim3(TPB_RF), 0, stream>>>(hist_part16, prm);
    k_main<<<dim3(NBATCH * NBPB_F), dim3(TPB), 0, stream>>>(pred4, mask4, prm, out, partials,
                                                            cand_cnt, cand_idx, cand_sb, cand_bce);
    k_fixup<<<dim3(NBATCH), dim3(TPB), 0, stream>>>(cand_cnt, cand_idx, cand_sb, cand_bce,
                                                    prm, out, tie_partials, partials, done_f);
}